// Round 5
// baseline (2230.501 us; speedup 1.0000x reference)
//
#include <hip/hip_runtime.h>
#include <hip/hip_bf16.h>
#include <math.h>

#define B_ 128
#define L_ 196
#define D_ 512
#define T_ 20
#define V_ 10000
#define E_ 256
#define H_ 512
#define A_ 512
#define TM1 19
#define ROWS (TM1*B_)      /* 2432 */
#define G4H 2048
#define KCAT 1024
#define NBLK 256
#define LH 98
#define SMEM_BYTES 153600

typedef unsigned short ushort_t;
typedef __attribute__((ext_vector_type(8))) short bf16x8;
typedef __attribute__((ext_vector_type(4))) float f32x4;

__device__ __forceinline__ float fast_tanh(float x){
    float ax = fabsf(x);
    float e = __expf(-2.f*ax);
    float r = __builtin_amdgcn_rcpf(1.f + e);
    return copysignf((1.f - e)*r, x);
}
__device__ __forceinline__ float sigmoidf_(float x){
    return __builtin_amdgcn_rcpf(1.f + __expf(-x));
}
__device__ __forceinline__ ushort_t f2b(float f){
    union{float f; unsigned u;} x; x.f = f;
    unsigned r = x.u + 0x7fffu + ((x.u>>16)&1u);
    return (ushort_t)(r>>16);
}
__device__ __forceinline__ float b2f(ushort_t h){
    union{unsigned u; float f;} x; x.u = ((unsigned)h)<<16;
    return x.f;
}
__device__ __forceinline__ float b2f_lo(unsigned u){ union{unsigned u; float f;} x; x.u = u<<16; return x.f; }
__device__ __forceinline__ float b2f_hi(unsigned u){ union{unsigned u; float f;} x; x.u = u & 0xffff0000u; return x.f; }

// ================= bf16 MFMA GEMM: C = A @ BT^T (+bias), swizzled LDS =================
template<int OUT_BF16, int HAS_BIAS, int NT, int SWZ>
__global__ __launch_bounds__(256)
void gemm_mfma(const ushort_t* __restrict__ A, int lda,
               const ushort_t* __restrict__ BT, int ldb,
               void* __restrict__ Cout, int ldc,
               int N, int K, const float* __restrict__ bias)
{
    __shared__ ushort_t As[128*32];
    __shared__ ushort_t Bs[128*32];
    int bm, bn;
    if (SWZ){
        int bid = blockIdx.x;                 // 0..1519
        int swz = (bid & 7)*190 + (bid >> 3); // XCD-contiguous chunks
        int mt = swz % 19, nt = swz / 19;     // nt 0..79
        if (nt >= 79) return;
        bm = mt*128; bn = nt*128;
    } else {
        bm = blockIdx.y * 128; bn = blockIdx.x * 128;
    }
    const int tid = threadIdx.x;
    const int lane = tid & 63;
    const int wave = tid >> 6;
    const int wm = (wave >> 1) * 64;
    const int wn = (wave & 1) * 64;
    const int lrow = lane & 15;
    const int lk8  = (lane >> 4) * 8;
    const int srow = tid >> 2;
    const int skq  = ((tid & 3) * 8) ^ ((srow & 3) << 3);   // write-side swizzle
    const int skq0 = (tid & 3) * 8;

    f32x4 acc[4][4];
    #pragma unroll
    for (int i=0;i<4;i++)
        #pragma unroll
        for (int j=0;j<4;j++) acc[i][j] = (f32x4){0.f,0.f,0.f,0.f};

    const ushort_t* Abase = A  + (size_t)(bm+srow)*lda + skq0;
    const ushort_t* Bbase = BT + (size_t)(bn+srow)*ldb + skq0;

    for (int k0 = 0; k0 < K; k0 += 32) {
        int4 a0 = *(const int4*)(Abase + k0);
        int4 a1 = *(const int4*)(Abase + (size_t)64*lda + k0);
        int4 b0 = *(const int4*)(Bbase + k0);
        int4 b1 = *(const int4*)(Bbase + (size_t)64*ldb + k0);
        __syncthreads();
        *(int4*)&As[srow*32 + skq]      = a0;
        *(int4*)&As[(srow+64)*32 + skq] = a1;
        *(int4*)&Bs[srow*32 + skq]      = b0;
        *(int4*)&Bs[(srow+64)*32 + skq] = b1;
        __syncthreads();
        bf16x8 af[4], bfr[4];
        #pragma unroll
        for (int i=0;i<4;i++){
            int r = wm + i*16 + lrow;
            af[i]  = *(bf16x8*)&As[r*32 + (lk8 ^ ((r & 3) << 3))];
        }
        #pragma unroll
        for (int j=0;j<4;j++){
            int r = wn + j*16 + lrow;
            bfr[j] = *(bf16x8*)&Bs[r*32 + (lk8 ^ ((r & 3) << 3))];
        }
        #pragma unroll
        for (int i=0;i<4;i++)
            #pragma unroll
            for (int j=0;j<4;j++)
                acc[i][j] = __builtin_amdgcn_mfma_f32_16x16x32_bf16(af[i], bfr[j], acc[i][j], 0, 0, 0);
    }

    const int rq = (lane >> 4) * 4;
    #pragma unroll
    for (int j=0;j<4;j++){
        int col = bn + wn + j*16 + lrow;
        if (col >= N) continue;
        float bv = HAS_BIAS ? bias[col] : 0.f;
        #pragma unroll
        for (int i=0;i<4;i++){
            #pragma unroll
            for (int q=0;q<4;q++){
                int row = bm + wm + i*16 + rq + q;
                float v = acc[i][j][q] + bv;
                if (OUT_BF16) ((ushort_t*)Cout)[(size_t)row*ldc + col] = f2b(v);
                else if (NT)  __builtin_nontemporal_store(v, &((float*)Cout)[(size_t)row*ldc + col]);
                else          ((float*)Cout)[(size_t)row*ldc + col] = v;
            }
        }
    }
}

// ============ f32 tile GEMM (init path): C = tanh(A@B + bias) ============
__global__ __launch_bounds__(256) void gemm64t(const float* __restrict__ A, int lda,
                       const float* __restrict__ Bm, int ldb,
                       float* __restrict__ C, int ldc, const float* __restrict__ bias)
{
    __shared__ float As[16][65];
    __shared__ float Bs[16][65];
    int bm = blockIdx.y*64, bn = blockIdx.x*64;
    int tid = threadIdx.x;
    int tx = tid & 15, ty = tid >> 4;
    float acc[4][4] = {};
    for (int k0 = 0; k0 < D_; k0 += 16) {
        {
            int r  = tid >> 2;
            int kq = (tid & 3) * 4;
            float4 va = *(const float4*)(A + (size_t)(bm+r)*lda + k0 + kq);
            As[kq+0][r]=va.x; As[kq+1][r]=va.y; As[kq+2][r]=va.z; As[kq+3][r]=va.w;
        }
        {
            int kk = tid >> 4;
            int nq = (tid & 15) * 4;
            float4 vb = *(const float4*)(Bm + (size_t)(k0+kk)*ldb + bn + nq);
            Bs[kk][nq+0]=vb.x; Bs[kk][nq+1]=vb.y; Bs[kk][nq+2]=vb.z; Bs[kk][nq+3]=vb.w;
        }
        __syncthreads();
        #pragma unroll
        for (int k = 0; k < 16; ++k) {
            float a0[4], b0[4];
            #pragma unroll
            for (int i=0;i<4;i++) a0[i] = As[k][ty*4+i];
            #pragma unroll
            for (int j=0;j<4;j++) b0[j] = Bs[k][tx*4+j];
            #pragma unroll
            for (int i=0;i<4;i++)
                #pragma unroll
                for (int j=0;j<4;j++)
                    acc[i][j] = fmaf(a0[i], b0[j], acc[i][j]);
        }
        __syncthreads();
    }
    #pragma unroll
    for (int i=0;i<4;i++){
        int row = bm + ty*4 + i;
        #pragma unroll
        for (int j=0;j<4;j++){
            int col = bn + tx*4 + j;
            C[(size_t)row*ldc + col] = fast_tanh(acc[i][j] + bias[col]);
        }
    }
}

// ================= prep kernels =================
__global__ void transpose_cvt(const float* __restrict__ src, const float* __restrict__ src2,
                              int lds_, int Ksz, int Nsz,
                              ushort_t* __restrict__ dst, int ldk, int koff)
{
    __shared__ float t[32][33];
    int n0 = blockIdx.x*32, k0 = blockIdx.y*32;
    int tx = threadIdx.x & 31, ty = threadIdx.x >> 5;
    #pragma unroll
    for (int kk = ty; kk < 32; kk += 8){
        int k = k0 + kk, n = n0 + tx;
        float v = 0.f;
        if (k < Ksz && n < Nsz){
            v = src[(size_t)k*lds_ + n];
            if (src2) v += src2[(size_t)k*lds_ + n];
        }
        t[kk][tx] = v;
    }
    __syncthreads();
    #pragma unroll
    for (int nn = ty; nn < 32; nn += 8){
        int n = n0 + nn, k = k0 + tx;
        if (k < Ksz) dst[(size_t)n*ldk + koff + k] = f2b(t[tx][nn]);
    }
}

__global__ void bias4h_k(const float* __restrict__ b_ih, const float* __restrict__ b_hh,
                         float* __restrict__ bias4h, unsigned* __restrict__ bar){
    int i = blockIdx.x*blockDim.x + threadIdx.x;
    if (i < G4H) bias4h[i] = b_ih[i] + b_hh[i];
    if (i == 0) *bar = 0u;
}

__global__ __launch_bounds__(256) void mean_cvt_k(const float* __restrict__ a, ushort_t* __restrict__ a_b,
                                                  float* __restrict__ mc){
    int idx = blockIdx.x*256 + threadIdx.x;   // b*512 + d
    int b = idx >> 9, d = idx & 511;
    const float* p = a + (size_t)b*L_*D_ + d;
    ushort_t* q = a_b + (size_t)b*L_*D_ + d;
    float s = 0.f;
    for (int l=0;l<L_;l++){ float v = p[(size_t)l*D_]; s += v; q[(size_t)l*D_] = f2b(v); }
    mc[idx] = s * (1.f/(float)L_);
}

__global__ void gather_emb(const int* __restrict__ captions, const float* __restrict__ embW,
                           ushort_t* __restrict__ xemb){
    int i = blockIdx.x;                 // t*B + b
    int t = i / B_, b = i - t*B_;
    int cap = captions[b*T_ + t];
    float4 v = ((const float4*)(embW + (size_t)cap*E_))[threadIdx.x];
    ushort_t r[4] = {f2b(v.x),f2b(v.y),f2b(v.z),f2b(v.w)};
    *(uint2*)(xemb + (size_t)i*E_ + threadIdx.x*4) = *(uint2*)r;
}

__global__ void cvt_h0_k(const float* __restrict__ h0f, ushort_t* __restrict__ hbuf){
    int idx = blockIdx.x*blockDim.x + threadIdx.x;
    hbuf[idx] = f2b(h0f[idx]);
}

// ================= persistent cooperative loop kernel =================
struct LoopArgs {
    const ushort_t* wa_b;
    const ushort_t* a_b;
    const float* v;
    const float* beta_W;
    const float* beta_b;
    const ushort_t* WcatT;
    const ushort_t* WhcT;
    const float* embWih;
    const float* cbuf0;
    ushort_t* hbuf;
    ushort_t* Hall;
    float* ebuf;
    float* ctxp;
    float* gp;
    float* alphas;
    unsigned* bar;
};

// hW = h @ Whc via MFMA (h broadcast in A row 0); result -> hWl[512] (f32, LDS)
__device__ __forceinline__ void hw_mfma_lds(const ushort_t* hls, const ushort_t* __restrict__ WhcT,
                                            float* hWl, int j){
    int lane = j & 63, wave = j >> 6;
    int wn = wave * 64;
    int col16 = lane & 15;
    int khi = (lane >> 4) * 8;
    bool a_on = (col16 == 0);
    f32x4 acc[4];
    #pragma unroll
    for (int f=0;f<4;f++) acc[f] = (f32x4){0.f,0.f,0.f,0.f};
    for (int kk=0; kk<16; kk++){
        bf16x8 af = (bf16x8){0,0,0,0,0,0,0,0};
        if (a_on) af = *(const bf16x8*)&hls[kk*32 + khi];
        #pragma unroll
        for (int f=0;f<4;f++){
            bf16x8 bf = *(const bf16x8*)(WhcT + (size_t)(wn + f*16 + col16)*512 + kk*32 + khi);
            acc[f] = __builtin_amdgcn_mfma_f32_16x16x32_bf16(af, bf, acc[f], 0, 0, 0);
        }
    }
    if (lane < 16){
        #pragma unroll
        for (int f=0;f<4;f++) hWl[wn + f*16 + lane] = acc[f][0];
    }
}

__device__ __forceinline__ void grid_sync(unsigned* bar, unsigned target){
    __syncthreads();
    if (threadIdx.x == 0){
        __threadfence();
        atomicAdd(bar, 1u);
        while (__hip_atomic_load(bar, __ATOMIC_ACQUIRE, __HIP_MEMORY_SCOPE_AGENT) < target){
            __builtin_amdgcn_s_sleep(1);
        }
    }
    __syncthreads();
}

__global__ __launch_bounds__(512) void loop_k(LoopArgs p){
    extern __shared__ char dyn[];
    ushort_t* wa_lds = (ushort_t*)dyn;            // [98][512] bf16, persistent
    float*    hWl    = (float*)(dyn + 100352);    // [512]
    float*    c_lds  = (float*)(dyn + 102400);    // [512]
    char*     stage  = dyn + 104448;              // 49152 B scratch

    const int blk = blockIdx.x;       // 0..255
    const int b   = blk >> 1;
    const int lh  = blk & 1;
    const int tid = threadIdx.x;      // 0..511
    const int lane = tid & 63, wave = tid >> 6;
    unsigned tgt = 0;

    // v in registers for the whole kernel
    const float* vp = p.v + lane*8;
    float4 v0 = *(const float4*)vp, v1 = *(const float4*)(vp+4);

    // ---- init: wa slice -> LDS, c -> LDS, hW(h0) ----
    {
        const ushort_t* src = p.wa_b + (size_t)(b*L_ + lh*LH)*512;
        for (int idx = tid; idx < LH*512/8; idx += 512)
            *(int4*)&wa_lds[idx*8] = *(const int4*)(src + (size_t)idx*8);
        c_lds[tid] = p.cbuf0[b*H_ + tid];
        ushort_t* hls = (ushort_t*)stage;
        hls[tid] = p.hbuf[b*H_ + tid];
        __syncthreads();
        hw_mfma_lds(hls, p.WhcT, hWl, tid);
        __syncthreads();
    }

    for (int t = 0; t < TM1; ++t){
        // ===== phase 1: e from LDS-resident wa =====
        {
            float4 hw0 = *(float4*)&hWl[lane*8];
            float4 hw1 = *(float4*)&hWl[lane*8 + 4];
            for (int ll = wave; ll < LH; ll += 8){
                int4 raw = *(int4*)&wa_lds[ll*512 + lane*8];
                const unsigned* u = (const unsigned*)&raw;
                float s;
                s  = fast_tanh(b2f_lo(u[0]) + hw0.x)*v0.x;
                s += fast_tanh(b2f_hi(u[0]) + hw0.y)*v0.y;
                s += fast_tanh(b2f_lo(u[1]) + hw0.z)*v0.z;
                s += fast_tanh(b2f_hi(u[1]) + hw0.w)*v0.w;
                s += fast_tanh(b2f_lo(u[2]) + hw1.x)*v1.x;
                s += fast_tanh(b2f_hi(u[2]) + hw1.y)*v1.y;
                s += fast_tanh(b2f_lo(u[3]) + hw1.z)*v1.z;
                s += fast_tanh(b2f_hi(u[3]) + hw1.w)*v1.w;
                #pragma unroll
                for (int off=32; off; off>>=1) s += __shfl_down(s, off);
                if (lane==0) p.ebuf[b*L_ + lh*LH + ll] = s;
            }
        }
        tgt += NBLK; grid_sync(p.bar, tgt);
        // ===== phase 2: softmax + beta + ctx partial (streams a_b half) =====
        {
            float* red_s = (float*)stage;            // [512]
            float* al_s  = (float*)(stage + 2048);   // [98]
            float ev = (tid < L_) ? p.ebuf[b*L_ + tid] : -3.0e38f;
            red_s[tid] = ev; __syncthreads();
            #pragma unroll
            for (int s=256; s; s>>=1){ if (tid<s) red_s[tid] = fmaxf(red_s[tid], red_s[tid+s]); __syncthreads(); }
            float m = red_s[0]; __syncthreads();
            float pr = (tid < L_) ? __expf(ev - m) : 0.f;
            red_s[tid] = pr; __syncthreads();
            #pragma unroll
            for (int s=256; s; s>>=1){ if (tid<s) red_s[tid] += red_s[tid+s]; __syncthreads(); }
            float inv = 1.f / red_s[0];
            __syncthreads();
            int tl = tid - lh*LH;
            if (tl >= 0 && tl < LH){
                float al = pr*inv;
                al_s[tl] = al;
                __builtin_nontemporal_store(al, p.alphas + (size_t)b*TM1*L_ + (size_t)t*L_ + tid);
            }
            // beta = sigmoid(h . beta_W + beta_b)
            float dv = b2f(p.hbuf[b*H_ + tid]) * p.beta_W[tid];
            red_s[tid] = dv; __syncthreads();
            #pragma unroll
            for (int s=256; s; s>>=1){ if (tid<s) red_s[tid] += red_s[tid+s]; __syncthreads(); }
            float beta = sigmoidf_(red_s[0] + p.beta_b[0]);
            // ctx partial over own l-half, all 512 d; d = tid
            const ushort_t* pa = p.a_b + (size_t)(b*L_ + lh*LH)*512 + tid;
            float s0 = 0.f;
            #pragma unroll 7
            for (int i=0; i<LH; ++i) s0 = fmaf(al_s[i], b2f(pa[(size_t)i*512]), s0);
            p.ctxp[(size_t)blk*512 + tid] = beta*s0;
        }
        tgt += NBLK; grid_sync(p.bar, tgt);
        // ===== phase 3: gates partials; block = (bn 0..31, ks 0..7), tile 128x64, K=128 =====
        {
            ushort_t* As = (ushort_t*)stage;     // [128][128] swizzled
            ushort_t* Bs = As + 128*128;         // [64][128] swizzled
            const int colbase = (blk & 31) * 64;
            const int ks = blk >> 5;
            if (ks < 4){
                for (int idx = tid; idx < 8192; idx += 512){
                    int r = idx >> 6, c = (idx & 63) * 2;
                    int kg = ks*128 + c;
                    float2 p0 = *(const float2*)(p.ctxp + (size_t)(2*r)*512 + kg);
                    float2 p1 = *(const float2*)(p.ctxp + (size_t)(2*r+1)*512 + kg);
                    unsigned pk = (unsigned)f2b(p0.x + p1.x) | (((unsigned)f2b(p0.y + p1.y))<<16);
                    *(unsigned*)&As[r*128 + (c ^ ((r & 7) << 3))] = pk;
                }
            } else {
                for (int idx = tid; idx < 2048; idx += 512){
                    int r = idx >> 4, cc = (idx & 15) * 8;
                    *(int4*)&As[r*128 + (cc ^ ((r & 7) << 3))] =
                        *(const int4*)(p.hbuf + (size_t)r*512 + (ks-4)*128 + cc);
                }
            }
            for (int idx = tid; idx < 1024; idx += 512){
                int r = idx >> 4, cc = (idx & 15) * 8;
                *(int4*)&Bs[r*128 + (cc ^ ((r & 7) << 3))] =
                    *(const int4*)(p.WcatT + (size_t)(colbase + r)*KCAT + ks*128 + cc);
            }
            __syncthreads();
            const int wm = (wave & 3) * 32, wn = (wave >> 2) * 32;
            const int lrow = lane & 15, lk8 = (lane >> 4) * 8;
            f32x4 acc[2][2];
            #pragma unroll
            for (int i=0;i<2;i++)
                #pragma unroll
                for (int j=0;j<2;j++) acc[i][j] = (f32x4){0.f,0.f,0.f,0.f};
            #pragma unroll
            for (int kk = 0; kk < 4; ++kk){
                bf16x8 af[2], bfr[2];
                #pragma unroll
                for (int i=0;i<2;i++){
                    int r = wm + i*16 + lrow;
                    af[i] = *(bf16x8*)&As[r*128 + ((kk*32 + lk8) ^ ((r & 7) << 3))];
                }
                #pragma unroll
                for (int j=0;j<2;j++){
                    int r = wn + j*16 + lrow;
                    bfr[j] = *(bf16x8*)&Bs[r*128 + ((kk*32 + lk8) ^ ((r & 7) << 3))];
                }
                #pragma unroll
                for (int i=0;i<2;i++)
                    #pragma unroll
                    for (int j=0;j<2;j++)
                        acc[i][j] = __builtin_amdgcn_mfma_f32_16x16x32_bf16(af[i], bfr[j], acc[i][j], 0, 0, 0);
            }
            const int rq = (lane >> 4) * 4;
            #pragma unroll
            for (int i=0;i<2;i++)
                #pragma unroll
                for (int j=0;j<2;j++){
                    int gcol = colbase + wn + j*16 + lrow;
                    #pragma unroll
                    for (int q=0;q<4;q++){
                        int grow = wm + i*16 + rq + q;
                        p.gp[((size_t)(ks*B_ + grow))*G4H + gcol] = acc[i][j][q];
                    }
                }
        }
        tgt += NBLK; grid_sync(p.bar, tgt);
        // ===== phase 4: lstm pointwise (dup per lh) + next hW =====
        {
            const int j = tid;
            const float* eb = p.embWih + ((size_t)(t*B_ + b))*G4H;
            float gi = eb[j], gf = eb[H_+j], gg = eb[2*H_+j], go = eb[3*H_+j];
            #pragma unroll
            for (int ks=0; ks<8; ks++){
                const float* g = p.gp + ((size_t)(ks*B_ + b))*G4H;
                gi += g[j]; gf += g[H_+j]; gg += g[2*H_+j]; go += g[3*H_+j];
            }
            float ig = sigmoidf_(gi), fg = sigmoidf_(gf);
            float g2 = fast_tanh(gg), og = sigmoidf_(go);
            float c = fg*c_lds[j] + ig*g2;
            float h = og*fast_tanh(c);
            c_lds[j] = c;
            ushort_t hb = f2b(h);
            p.hbuf[b*H_ + j] = hb;
            p.Hall[((size_t)t*B_ + b)*H_ + j] = hb;
            ushort_t* hls = (ushort_t*)stage;
            hls[j] = hb;
            __syncthreads();
            hw_mfma_lds(hls, p.WhcT, hWl, j);
            __syncthreads();
        }
        // no grid barrier: next phase-1 uses only this block's hWl/wa_lds
    }
}

extern "C" void kernel_launch(void* const* d_in, const int* in_sizes, int n_in,
                              void* d_out, int out_size, void* d_ws, size_t ws_size,
                              hipStream_t stream) {
    const float* a      = (const float*)d_in[0];
    const int*   caps   = (const int*)  d_in[1];
    const float* embW   = (const float*)d_in[3];
    const float* Wa     = (const float*)d_in[4];
    const float* Wh     = (const float*)d_in[5];
    const float* Wc     = (const float*)d_in[6];
    const float* v      = (const float*)d_in[7];
    const float* beta_W = (const float*)d_in[8];
    const float* beta_b = (const float*)d_in[9];
    const float* W_ih   = (const float*)d_in[10];
    const float* W_hh   = (const float*)d_in[11];
    const float* b_ih   = (const float*)d_in[12];
    const float* b_hh   = (const float*)d_in[13];
    const float* fc_W   = (const float*)d_in[14];
    const float* fc_b   = (const float*)d_in[15];
    const float* iWh    = (const float*)d_in[16];
    const float* ibh    = (const float*)d_in[17];
    const float* iWc    = (const float*)d_in[18];
    const float* ibc    = (const float*)d_in[19];

    float* out    = (float*)d_out;
    float* alphas = out + (size_t)ROWS*V_;

    // d_out scratch (dead before final logits GEMM overwrites it)
    char* ob = (char*)d_out;
    ushort_t* wa_b   = (ushort_t*)(ob);               // 25,690,112 B
    ushort_t* a_b    = (ushort_t*)(ob + 25690112);    // 25,690,112 B
    float*    embWih = (float*)   (ob + 51380224);    // 19,922,944 B

    // d_ws layout (byte offsets)
    char* wb = (char*)d_ws;
    float* mean_ctx = (float*)(wb);                 // 262144
    float* cbuf     = (float*)(wb + 262144);        // 262144
    float* h0f      = (float*)(wb + 524288);        // 262144
    unsigned* bar   = (unsigned*)(wb + 786432);     // 4 (pad)
    float* bias4h   = (float*)(wb + 787456);        // 8192
    float* ebuf     = (float*)(wb + 795648);        // 100352
    float* ctxp     = (float*)(wb + 896000);        // 524288
    ushort_t* hbuf  = (ushort_t*)(wb + 1420288);    // 131072
    float* gp       = (float*)(wb + 1551360);       // 8388608
    ushort_t* xemb_b = (ushort_t*)(wb + 9939968);   // 1245184
    ushort_t* Hall   = (ushort_t*)(wb + 11185152);  // 2490368
    ushort_t* WaT    = (ushort_t*)(wb + 13675520);  // 524288
    ushort_t* WhcT   = (ushort_t*)(wb + 14199808);  // 524288
    ushort_t* WihT   = (ushort_t*)(wb + 14724096);  // 1048576
    ushort_t* WcatT  = (ushort_t*)(wb + 15772672);  // 4194304
    ushort_t* fcWT   = (ushort_t*)(wb + 19966976);  // 10354688 -> ends ~30.3MB

    // ---- prep ----
    bias4h_k<<<8, 256, 0, stream>>>(b_ih, b_hh, bias4h, bar);
    transpose_cvt<<<dim3(16,16), 256, 0, stream>>>(Wa, nullptr, A_, D_, A_, WaT, 512, 0);
    transpose_cvt<<<dim3(16,16), 256, 0, stream>>>(Wh, Wc,      A_, H_, A_, WhcT, 512, 0);
    transpose_cvt<<<dim3(64,8),  256, 0, stream>>>(W_ih, nullptr, G4H, E_, G4H, WihT, 256, 0);
    transpose_cvt<<<dim3(64,16), 256, 0, stream>>>(W_ih + (size_t)E_*G4H, nullptr, G4H, D_, G4H, WcatT, KCAT, 0);
    transpose_cvt<<<dim3(64,16), 256, 0, stream>>>(W_hh, nullptr, G4H, H_, G4H, WcatT, KCAT, 512);
    transpose_cvt<<<dim3(316,16),256, 0, stream>>>(fc_W, nullptr, V_, H_, V_, fcWT, 512, 0);
    mean_cvt_k<<<256, 256, 0, stream>>>(a, a_b, mean_ctx);
    gather_emb<<<ROWS, 64, 0, stream>>>(caps, embW, xemb_b);

    gemm64t<<<dim3(8,2), 256, 0, stream>>>(mean_ctx, D_, iWh, H_, h0f, H_, ibh);
    gemm64t<<<dim3(8,2), 256, 0, stream>>>(mean_ctx, D_, iWc, H_, cbuf, H_, ibc);
    cvt_h0_k<<<256, 256, 0, stream>>>(h0f, hbuf);

    // wa_b = bf16(a @ Wa)    (25088 x 512 x 512)
    gemm_mfma<1,0,0,0><<<dim3(4,196), 256, 0, stream>>>(a_b, D_, WaT, D_, wa_b, A_, A_, D_, nullptr);
    // embWih = xemb @ W_ih[:E] + (b_ih+b_hh)   (2432 x 2048 x 256)
    gemm_mfma<0,1,0,0><<<dim3(16,19), 256, 0, stream>>>(xemb_b, E_, WihT, E_, embWih, G4H, G4H, E_, bias4h);

    // ---- persistent 19-step loop (cooperative, wa pinned in LDS) ----
    static int smem_set = 0;
    if (!smem_set){
        hipFuncSetAttribute((const void*)loop_k, hipFuncAttributeMaxDynamicSharedMemorySize, SMEM_BYTES);
        smem_set = 1;
    }
    LoopArgs la;
    la.wa_b = wa_b; la.a_b = a_b; la.v = v; la.beta_W = beta_W; la.beta_b = beta_b;
    la.WcatT = WcatT; la.WhcT = WhcT; la.embWih = embWih; la.cbuf0 = cbuf;
    la.hbuf = hbuf; la.Hall = Hall; la.ebuf = ebuf; la.ctxp = ctxp;
    la.gp = gp; la.alphas = alphas; la.bar = bar;
    void* kargs[] = { &la };
    hipLaunchCooperativeKernel((const void*)loop_k, dim3(NBLK), dim3(512), kargs, SMEM_BYTES, stream);

    // logits = Hall @ fc_W + fc_b   (2432 x 10000 x 512), NT stores + XCD swizzle
    gemm_mfma<0,1,1,1><<<dim3(1520), 256, 0, stream>>>(Hall, H_, fcWT, H_, out, V_, V_, H_, fc_b);
}

// Round 6
// 1140.890 us; speedup vs baseline: 1.9551x; 1.9551x over previous
//
#include <hip/hip_runtime.h>
#include <hip/hip_bf16.h>
#include <math.h>

#define B_ 128
#define L_ 196
#define D_ 512
#define T_ 20
#define V_ 10000
#define E_ 256
#define H_ 512
#define A_ 512
#define TM1 19
#define ROWS (TM1*B_)      /* 2432 */
#define G4H 2048
#define KCAT 1024
#define LH 98

typedef unsigned short ushort_t;
typedef __attribute__((ext_vector_type(8))) short bf16x8;
typedef __attribute__((ext_vector_type(4))) float f32x4;

__device__ __forceinline__ float fast_tanh(float x){
    float ax = fabsf(x);
    float e = __expf(-2.f*ax);
    float r = __builtin_amdgcn_rcpf(1.f + e);
    return copysignf((1.f - e)*r, x);
}
__device__ __forceinline__ float sigmoidf_(float x){
    return __builtin_amdgcn_rcpf(1.f + __expf(-x));
}
__device__ __forceinline__ ushort_t f2b(float f){
    union{float f; unsigned u;} x; x.f = f;
    unsigned r = x.u + 0x7fffu + ((x.u>>16)&1u);
    return (ushort_t)(r>>16);
}
__device__ __forceinline__ float b2f(ushort_t h){
    union{unsigned u; float f;} x; x.u = ((unsigned)h)<<16;
    return x.f;
}
__device__ __forceinline__ float b2f_lo(unsigned u){ union{unsigned u; float f;} x; x.u = u<<16; return x.f; }
__device__ __forceinline__ float b2f_hi(unsigned u){ union{unsigned u; float f;} x; x.u = u & 0xffff0000u; return x.f; }

// ================= bf16 MFMA GEMM: C = A @ BT^T (+bias), swizzled LDS =================
template<int OUT_BF16, int HAS_BIAS, int NT, int SWZ>
__global__ __launch_bounds__(256)
void gemm_mfma(const ushort_t* __restrict__ A, int lda,
               const ushort_t* __restrict__ BT, int ldb,
               void* __restrict__ Cout, int ldc,
               int N, int K, const float* __restrict__ bias)
{
    __shared__ ushort_t As[128*32];
    __shared__ ushort_t Bs[128*32];
    int bm, bn;
    if (SWZ){
        int bid = blockIdx.x;                 // 0..1519
        int swz = (bid & 7)*190 + (bid >> 3); // XCD-contiguous chunks
        int mt = swz % 19, nt = swz / 19;     // nt 0..79
        if (nt >= 79) return;
        bm = mt*128; bn = nt*128;
    } else {
        bm = blockIdx.y * 128; bn = blockIdx.x * 128;
    }
    const int tid = threadIdx.x;
    const int lane = tid & 63;
    const int wave = tid >> 6;
    const int wm = (wave >> 1) * 64;
    const int wn = (wave & 1) * 64;
    const int lrow = lane & 15;
    const int lk8  = (lane >> 4) * 8;
    const int srow = tid >> 2;
    const int skq  = ((tid & 3) * 8) ^ ((srow & 3) << 3);   // write-side swizzle
    const int skq0 = (tid & 3) * 8;

    f32x4 acc[4][4];
    #pragma unroll
    for (int i=0;i<4;i++)
        #pragma unroll
        for (int j=0;j<4;j++) acc[i][j] = (f32x4){0.f,0.f,0.f,0.f};

    const ushort_t* Abase = A  + (size_t)(bm+srow)*lda + skq0;
    const ushort_t* Bbase = BT + (size_t)(bn+srow)*ldb + skq0;

    for (int k0 = 0; k0 < K; k0 += 32) {
        int4 a0 = *(const int4*)(Abase + k0);
        int4 a1 = *(const int4*)(Abase + (size_t)64*lda + k0);
        int4 b0 = *(const int4*)(Bbase + k0);
        int4 b1 = *(const int4*)(Bbase + (size_t)64*ldb + k0);
        __syncthreads();
        *(int4*)&As[srow*32 + skq]      = a0;
        *(int4*)&As[(srow+64)*32 + skq] = a1;
        *(int4*)&Bs[srow*32 + skq]      = b0;
        *(int4*)&Bs[(srow+64)*32 + skq] = b1;
        __syncthreads();
        bf16x8 af[4], bfr[4];
        #pragma unroll
        for (int i=0;i<4;i++){
            int r = wm + i*16 + lrow;
            af[i]  = *(bf16x8*)&As[r*32 + (lk8 ^ ((r & 3) << 3))];
        }
        #pragma unroll
        for (int j=0;j<4;j++){
            int r = wn + j*16 + lrow;
            bfr[j] = *(bf16x8*)&Bs[r*32 + (lk8 ^ ((r & 3) << 3))];
        }
        #pragma unroll
        for (int i=0;i<4;i++)
            #pragma unroll
            for (int j=0;j<4;j++)
                acc[i][j] = __builtin_amdgcn_mfma_f32_16x16x32_bf16(af[i], bfr[j], acc[i][j], 0, 0, 0);
    }

    const int rq = (lane >> 4) * 4;
    #pragma unroll
    for (int j=0;j<4;j++){
        int col = bn + wn + j*16 + lrow;
        if (col >= N) continue;
        float bv = HAS_BIAS ? bias[col] : 0.f;
        #pragma unroll
        for (int i=0;i<4;i++){
            #pragma unroll
            for (int q=0;q<4;q++){
                int row = bm + wm + i*16 + rq + q;
                float v = acc[i][j][q] + bv;
                if (OUT_BF16) ((ushort_t*)Cout)[(size_t)row*ldc + col] = f2b(v);
                else if (NT)  __builtin_nontemporal_store(v, &((float*)Cout)[(size_t)row*ldc + col]);
                else          ((float*)Cout)[(size_t)row*ldc + col] = v;
            }
        }
    }
}

// ============ f32 tile GEMM (init path): C = tanh(A@B + bias) ============
__global__ __launch_bounds__(256) void gemm64t(const float* __restrict__ A, int lda,
                       const float* __restrict__ Bm, int ldb,
                       float* __restrict__ C, int ldc, const float* __restrict__ bias)
{
    __shared__ float As[16][65];
    __shared__ float Bs[16][65];
    int bm = blockIdx.y*64, bn = blockIdx.x*64;
    int tid = threadIdx.x;
    int tx = tid & 15, ty = tid >> 4;
    float acc[4][4] = {};
    for (int k0 = 0; k0 < D_; k0 += 16) {
        {
            int r  = tid >> 2;
            int kq = (tid & 3) * 4;
            float4 va = *(const float4*)(A + (size_t)(bm+r)*lda + k0 + kq);
            As[kq+0][r]=va.x; As[kq+1][r]=va.y; As[kq+2][r]=va.z; As[kq+3][r]=va.w;
        }
        {
            int kk = tid >> 4;
            int nq = (tid & 15) * 4;
            float4 vb = *(const float4*)(Bm + (size_t)(k0+kk)*ldb + bn + nq);
            Bs[kk][nq+0]=vb.x; Bs[kk][nq+1]=vb.y; Bs[kk][nq+2]=vb.z; Bs[kk][nq+3]=vb.w;
        }
        __syncthreads();
        #pragma unroll
        for (int k = 0; k < 16; ++k) {
            float a0[4], b0[4];
            #pragma unroll
            for (int i=0;i<4;i++) a0[i] = As[k][ty*4+i];
            #pragma unroll
            for (int j=0;j<4;j++) b0[j] = Bs[k][tx*4+j];
            #pragma unroll
            for (int i=0;i<4;i++)
                #pragma unroll
                for (int j=0;j<4;j++)
                    acc[i][j] = fmaf(a0[i], b0[j], acc[i][j]);
        }
        __syncthreads();
    }
    #pragma unroll
    for (int i=0;i<4;i++){
        int row = bm + ty*4 + i;
        #pragma unroll
        for (int j=0;j<4;j++){
            int col = bn + tx*4 + j;
            C[(size_t)row*ldc + col] = fast_tanh(acc[i][j] + bias[col]);
        }
    }
}

// ================= prep kernels =================
__global__ void transpose_cvt(const float* __restrict__ src, const float* __restrict__ src2,
                              int lds_, int Ksz, int Nsz,
                              ushort_t* __restrict__ dst, int ldk, int koff)
{
    __shared__ float t[32][33];
    int n0 = blockIdx.x*32, k0 = blockIdx.y*32;
    int tx = threadIdx.x & 31, ty = threadIdx.x >> 5;
    #pragma unroll
    for (int kk = ty; kk < 32; kk += 8){
        int k = k0 + kk, n = n0 + tx;
        float v = 0.f;
        if (k < Ksz && n < Nsz){
            v = src[(size_t)k*lds_ + n];
            if (src2) v += src2[(size_t)k*lds_ + n];
        }
        t[kk][tx] = v;
    }
    __syncthreads();
    #pragma unroll
    for (int nn = ty; nn < 32; nn += 8){
        int n = n0 + nn, k = k0 + tx;
        if (k < Ksz) dst[(size_t)n*ldk + koff + k] = f2b(t[tx][nn]);
    }
}

__global__ void bias4h_k(const float* __restrict__ b_ih, const float* __restrict__ b_hh,
                         float* __restrict__ bias4h, unsigned* __restrict__ ebar){
    int i = blockIdx.x*blockDim.x + threadIdx.x;
    if (i < G4H) bias4h[i] = b_ih[i] + b_hh[i];
    if (i < B_) ebar[i] = 0u;
}

__global__ __launch_bounds__(256) void mean_cvt_k(const float* __restrict__ a, ushort_t* __restrict__ a_b,
                                                  float* __restrict__ mc){
    int idx = blockIdx.x*256 + threadIdx.x;   // b*512 + d
    int b = idx >> 9, d = idx & 511;
    const float* p = a + (size_t)b*L_*D_ + d;
    ushort_t* q = a_b + (size_t)b*L_*D_ + d;
    float s = 0.f;
    for (int l=0;l<L_;l++){ float v = p[(size_t)l*D_]; s += v; q[(size_t)l*D_] = f2b(v); }
    mc[idx] = s * (1.f/(float)L_);
}

__global__ void gather_emb(const int* __restrict__ captions, const float* __restrict__ embW,
                           ushort_t* __restrict__ xemb){
    int i = blockIdx.x;                 // t*B + b
    int t = i / B_, b = i - t*B_;
    int cap = captions[b*T_ + t];
    float4 v = ((const float4*)(embW + (size_t)cap*E_))[threadIdx.x];
    ushort_t r[4] = {f2b(v.x),f2b(v.y),f2b(v.z),f2b(v.w)};
    *(uint2*)(xemb + (size_t)i*E_ + threadIdx.x*4) = *(uint2*)r;
}

__global__ void cvt_h0_k(const float* __restrict__ h0f, ushort_t* __restrict__ xcat){
    int idx = blockIdx.x*blockDim.x + threadIdx.x;   // b*512 + j
    int b = idx >> 9, j = idx & 511;
    xcat[(size_t)b*KCAT + D_ + j] = f2b(h0f[idx]);
}

// ================= hW via MFMA (h in A-row0 trick) =================
__device__ __forceinline__ void hw_mfma_phase(const ushort_t* hls, const ushort_t* __restrict__ WhcT,
                                              float* __restrict__ hW, int b, int j){
    int lane = j & 63, wave = j >> 6;
    int wn = wave * 64;
    int col16 = lane & 15;
    int khi = (lane >> 4) * 8;
    bool a_on = (col16 == 0);
    f32x4 acc[4];
    #pragma unroll
    for (int f=0;f<4;f++) acc[f] = (f32x4){0.f,0.f,0.f,0.f};
    for (int kk=0; kk<16; kk++){
        bf16x8 af = (bf16x8){0,0,0,0,0,0,0,0};
        if (a_on) af = *(const bf16x8*)&hls[kk*32 + khi];
        #pragma unroll
        for (int f=0;f<4;f++){
            bf16x8 bf = *(const bf16x8*)(WhcT + (size_t)(wn + f*16 + col16)*512 + kk*32 + khi);
            acc[f] = __builtin_amdgcn_mfma_f32_16x16x32_bf16(af, bf, acc[f], 0, 0, 0);
        }
    }
    if (lane < 16){
        #pragma unroll
        for (int f=0;f<4;f++) hW[b*512 + wn + f*16 + lane] = acc[f][0];
    }
}

__global__ __launch_bounds__(512) void hw0_k(const ushort_t* __restrict__ xcat,
                                             const ushort_t* __restrict__ WhcT, float* __restrict__ hW){
    int b = blockIdx.x, j = threadIdx.x;
    __shared__ ushort_t hls[512];
    hls[j] = xcat[(size_t)b*KCAT + D_ + j];
    __syncthreads();
    hw_mfma_phase(hls, WhcT, hW, b, j);
}

// ================= fused attention: e + softmax + beta + ctx =================
// grid (B_, 2) x 512; pair-sync via monotonic ebar[b]
__global__ __launch_bounds__(512) void attn_k(const ushort_t* __restrict__ wa,
                        const ushort_t* __restrict__ a_b,
                        const float* __restrict__ hW,
                        const float* __restrict__ v,
                        const float* __restrict__ beta_W, const float* __restrict__ beta_b,
                        ushort_t* __restrict__ xcat, float* __restrict__ alphas_out,
                        float* __restrict__ ebuf, unsigned* __restrict__ ebar, int t)
{
    const int b = blockIdx.x, half = blockIdx.y;
    const int tid = threadIdx.x;
    const int lane = tid & 63, wave = tid >> 6;
    __shared__ float red[512];
    __shared__ float al_s[224];
    __shared__ float part[2][256];

    const float* hp = hW + b*512 + lane*8;
    float4 hw0 = *(const float4*)hp, hw1 = *(const float4*)(hp+4);
    const float* vp = v + lane*8;
    float4 v0 = *(const float4*)vp, v1 = *(const float4*)(vp+4);

    const int l0 = half*LH;
    for (int r = wave; r < LH; r += 8){
        int4 raw = *(const int4*)(wa + (((size_t)(b*L_ + l0 + r))<<9) + lane*8);
        const unsigned* u = (const unsigned*)&raw;
        float s;
        s  = fast_tanh(b2f_lo(u[0]) + hw0.x)*v0.x;
        s += fast_tanh(b2f_hi(u[0]) + hw0.y)*v0.y;
        s += fast_tanh(b2f_lo(u[1]) + hw0.z)*v0.z;
        s += fast_tanh(b2f_hi(u[1]) + hw0.w)*v0.w;
        s += fast_tanh(b2f_lo(u[2]) + hw1.x)*v1.x;
        s += fast_tanh(b2f_hi(u[2]) + hw1.y)*v1.y;
        s += fast_tanh(b2f_lo(u[3]) + hw1.z)*v1.z;
        s += fast_tanh(b2f_hi(u[3]) + hw1.w)*v1.w;
        #pragma unroll
        for (int off=32; off; off>>=1) s += __shfl_down(s, off);
        if (lane==0) ebuf[b*L_ + l0 + r] = s;
    }
    // ---- pair barrier (monotonic counter; 2 participants) ----
    __syncthreads();
    if (tid == 0){
        __threadfence();
        atomicAdd(&ebar[b], 1u);
        const unsigned tgt = 2u*(unsigned)(t+1);
        while (__hip_atomic_load(&ebar[b], __ATOMIC_ACQUIRE, __HIP_MEMORY_SCOPE_AGENT) < tgt)
            __builtin_amdgcn_s_sleep(1);
    }
    __syncthreads();
    // ---- softmax over all 196 (redundant in both halves) ----
    float ev = (tid < L_) ? ebuf[b*L_ + tid] : -3.0e38f;
    red[tid] = ev; __syncthreads();
    #pragma unroll
    for (int s=256; s; s>>=1){ if (tid<s) red[tid] = fmaxf(red[tid], red[tid+s]); __syncthreads(); }
    float m = red[0]; __syncthreads();
    float pr = (tid < L_) ? __expf(ev - m) : 0.f;
    red[tid] = pr; __syncthreads();
    #pragma unroll
    for (int s=256; s; s>>=1){ if (tid<s) red[tid] += red[tid+s]; __syncthreads(); }
    float inv = 1.f / red[0];
    __syncthreads();
    if (tid < L_) al_s[tid] = pr*inv;
    if (tid >= l0 && tid < l0 + LH)
        __builtin_nontemporal_store(pr*inv, alphas_out + (size_t)b*TM1*L_ + (size_t)t*L_ + tid);
    // ---- beta ----
    float dv = b2f(xcat[(size_t)b*KCAT + D_ + tid]) * beta_W[tid];
    red[tid] = dv; __syncthreads();
    #pragma unroll
    for (int s=256; s; s>>=1){ if (tid<s) red[tid] += red[tid+s]; __syncthreads(); }
    float beta = sigmoidf_(red[0] + beta_b[0]);
    __syncthreads();
    // ---- ctx: 256 d's per block, l split in two by tid>>8 ----
    const int d  = half*256 + (tid & 255);
    const int lr = tid >> 8;                       // 0/1
    const ushort_t* pa = a_b + (((size_t)(b*L_ + lr*LH))<<9) + d;
    float s0 = 0.f;
    #pragma unroll 7
    for (int i=0; i<LH; ++i) s0 = fmaf(al_s[lr*LH + i], b2f(pa[(size_t)i*512]), s0);
    part[lr][tid & 255] = s0;
    __syncthreads();
    if (tid < 256)
        xcat[(size_t)b*KCAT + half*256 + tid] = f2b(beta*(part[0][tid] + part[1][tid]));
}

// gates partials: grid (32, 4) x 256; tile M128 x N64, K-chunk 256
__global__ __launch_bounds__(256) void gates_k(const ushort_t* __restrict__ xcat,
                        const ushort_t* __restrict__ WcatT, float* __restrict__ gp){
    __shared__ ushort_t As[128*32];
    __shared__ ushort_t Bs[64*32];
    const int bn = blockIdx.x*64;
    const int ks = blockIdx.y;
    const int tid = threadIdx.x;
    const int lane = tid & 63, wave = tid >> 6;
    const int wm = wave*32;
    const int lrow = lane & 15;
    const int lk8 = (lane >> 4) * 8;
    f32x4 acc[2][4];
    #pragma unroll
    for (int i=0;i<2;i++)
        #pragma unroll
        for (int j=0;j<4;j++) acc[i][j] = (f32x4){0.f,0.f,0.f,0.f};

    for (int kk = 0; kk < 8; ++kk){
        int k0 = ks*256 + kk*32;
        int c0 = 2*tid;
        int r0 = c0 >> 2,  kq0 = (c0 & 3)*8;
        int r1 = (c0+1) >> 2, kq1 = ((c0+1) & 3)*8;
        int4 a0 = *(const int4*)(xcat + (size_t)r0*KCAT + k0 + kq0);
        int4 a1 = *(const int4*)(xcat + (size_t)r1*KCAT + k0 + kq1);
        int rb = tid >> 2, kqb = (tid & 3)*8;
        int4 b0 = *(const int4*)(WcatT + (size_t)(bn+rb)*KCAT + k0 + kqb);
        __syncthreads();
        *(int4*)&As[r0*32 + kq0] = a0;
        *(int4*)&As[r1*32 + kq1] = a1;
        *(int4*)&Bs[rb*32 + kqb] = b0;
        __syncthreads();
        bf16x8 af[2], bfr[4];
        #pragma unroll
        for (int i=0;i<2;i++) af[i] = *(bf16x8*)&As[(wm + i*16 + lrow)*32 + lk8];
        #pragma unroll
        for (int j=0;j<4;j++) bfr[j] = *(bf16x8*)&Bs[(j*16 + lrow)*32 + lk8];
        #pragma unroll
        for (int i=0;i<2;i++)
            #pragma unroll
            for (int j=0;j<4;j++)
                acc[i][j] = __builtin_amdgcn_mfma_f32_16x16x32_bf16(af[i], bfr[j], acc[i][j], 0, 0, 0);
    }
    const int rq = (lane >> 4) * 4;
    #pragma unroll
    for (int i=0;i<2;i++){
        #pragma unroll
        for (int j=0;j<4;j++){
            int gcol = bn + j*16 + lrow;
            #pragma unroll
            for (int q=0;q<4;q++){
                int grow = wm + i*16 + rq + q;
                gp[((size_t)(ks*B_ + grow))*G4H + gcol] = acc[i][j][q];
            }
        }
    }
}

// lstm pointwise (+ksplit reduce) + next-step hW;  grid B_ x 512
__global__ __launch_bounds__(512) void lstm_hw_k(const float* __restrict__ gp, const float* __restrict__ embWih,
                       float* __restrict__ cbuf, ushort_t* __restrict__ xcat, ushort_t* __restrict__ Hall,
                       const ushort_t* __restrict__ WhcT, float* __restrict__ hW, int t){
    int b = blockIdx.x, j = threadIdx.x;
    __shared__ ushort_t hls[512];
    float gi, gf, gg, go;
    {
        const float* eb = embWih + ((size_t)(t*B_ + b))*G4H;
        gi = eb[j]; gf = eb[H_+j]; gg = eb[2*H_+j]; go = eb[3*H_+j];
    }
    #pragma unroll
    for (int ks=0; ks<4; ks++){
        const float* g = gp + ((size_t)(ks*B_ + b))*G4H;
        gi += g[j]; gf += g[H_+j]; gg += g[2*H_+j]; go += g[3*H_+j];
    }
    float ig = sigmoidf_(gi), fg = sigmoidf_(gf);
    float g2 = fast_tanh(gg), og = sigmoidf_(go);
    float c = fg*cbuf[b*H_+j] + ig*g2;
    float h = og*fast_tanh(c);
    cbuf[b*H_+j] = c;
    ushort_t hb = f2b(h);
    xcat[(size_t)b*KCAT + D_ + j] = hb;
    Hall[((size_t)t*B_ + b)*H_ + j] = hb;
    hls[j] = hb;
    __syncthreads();
    hw_mfma_phase(hls, WhcT, hW, b, j);
}

extern "C" void kernel_launch(void* const* d_in, const int* in_sizes, int n_in,
                              void* d_out, int out_size, void* d_ws, size_t ws_size,
                              hipStream_t stream) {
    const float* a      = (const float*)d_in[0];
    const int*   caps   = (const int*)  d_in[1];
    const float* embW   = (const float*)d_in[3];
    const float* Wa     = (const float*)d_in[4];
    const float* Wh     = (const float*)d_in[5];
    const float* Wc     = (const float*)d_in[6];
    const float* v      = (const float*)d_in[7];
    const float* beta_W = (const float*)d_in[8];
    const float* beta_b = (const float*)d_in[9];
    const float* W_ih   = (const float*)d_in[10];
    const float* W_hh   = (const float*)d_in[11];
    const float* b_ih   = (const float*)d_in[12];
    const float* b_hh   = (const float*)d_in[13];
    const float* fc_W   = (const float*)d_in[14];
    const float* fc_b   = (const float*)d_in[15];
    const float* iWh    = (const float*)d_in[16];
    const float* ibh    = (const float*)d_in[17];
    const float* iWc    = (const float*)d_in[18];
    const float* ibc    = (const float*)d_in[19];

    float* out    = (float*)d_out;
    float* alphas = out + (size_t)ROWS*V_;

    // d_out scratch (dead before final logits GEMM overwrites it)
    char* ob = (char*)d_out;
    ushort_t* wa_b   = (ushort_t*)(ob);               // 25,690,112 B
    ushort_t* a_b    = (ushort_t*)(ob + 25690112);    // 25,690,112 B
    float*    embWih = (float*)   (ob + 51380224);    // 19,922,944 B (ends 71.3MB < 97.28MB)

    // d_ws layout (byte offsets)
    char* wb = (char*)d_ws;
    float* mean_ctx = (float*)(wb);              // 262144
    float* cbuf     = (float*)(wb + 262144);     // 262144
    float* h0f      = (float*)(wb + 524288);     // 262144
    float* hWbuf    = (float*)(wb + 786432);     // 262144
    float* ebuf     = (float*)(wb + 1048576);    // 131072
    float* bias4h   = (float*)(wb + 1179648);    // 8192
    float* gp       = (float*)(wb + 1187840);    // 4194304
    ushort_t* xcat_b = (ushort_t*)(wb + 5382144);   // 262144
    ushort_t* xemb_b = (ushort_t*)(wb + 5644288);   // 1245184
    ushort_t* Hall   = (ushort_t*)(wb + 6889472);   // 2490368
    ushort_t* WaT    = (ushort_t*)(wb + 9379840);   // 524288
    ushort_t* WhcT   = (ushort_t*)(wb + 9904128);   // 524288
    ushort_t* WihT   = (ushort_t*)(wb + 10428416);  // 1048576
    ushort_t* WcatT  = (ushort_t*)(wb + 11476992);  // 4194304
    ushort_t* fcWT   = (ushort_t*)(wb + 15671296);  // 10354688
    unsigned* ebar   = (unsigned*)(wb + 26025984);  // 512 -> ends ~26MB

    // ---- prep ----
    bias4h_k<<<8, 256, 0, stream>>>(b_ih, b_hh, bias4h, ebar);
    transpose_cvt<<<dim3(16,16), 256, 0, stream>>>(Wa, nullptr, A_, D_, A_, WaT, 512, 0);
    transpose_cvt<<<dim3(16,16), 256, 0, stream>>>(Wh, Wc,      A_, H_, A_, WhcT, 512, 0);
    transpose_cvt<<<dim3(64,8),  256, 0, stream>>>(W_ih, nullptr, G4H, E_, G4H, WihT, 256, 0);
    transpose_cvt<<<dim3(64,16), 256, 0, stream>>>(W_ih + (size_t)E_*G4H, nullptr, G4H, D_, G4H, WcatT, KCAT, 0);
    transpose_cvt<<<dim3(64,16), 256, 0, stream>>>(W_hh, nullptr, G4H, H_, G4H, WcatT, KCAT, 512);
    transpose_cvt<<<dim3(316,16),256, 0, stream>>>(fc_W, nullptr, V_, H_, V_, fcWT, 512, 0);
    mean_cvt_k<<<256, 256, 0, stream>>>(a, a_b, mean_ctx);
    gather_emb<<<ROWS, 64, 0, stream>>>(caps, embW, xemb_b);

    gemm64t<<<dim3(8,2), 256, 0, stream>>>(mean_ctx, D_, iWh, H_, h0f, H_, ibh);
    gemm64t<<<dim3(8,2), 256, 0, stream>>>(mean_ctx, D_, iWc, H_, cbuf, H_, ibc);
    cvt_h0_k<<<256, 256, 0, stream>>>(h0f, xcat_b);
    hw0_k<<<B_, 512, 0, stream>>>(xcat_b, WhcT, hWbuf);

    // wa_b = bf16(a @ Wa)    (25088 x 512 x 512)
    gemm_mfma<1,0,0,0><<<dim3(4,196), 256, 0, stream>>>(a_b, D_, WaT, D_, wa_b, A_, A_, D_, nullptr);
    // embWih = xemb @ W_ih[:E] + (b_ih+b_hh)   (2432 x 2048 x 256)
    gemm_mfma<0,1,0,0><<<dim3(16,19), 256, 0, stream>>>(xemb_b, E_, WihT, E_, embWih, G4H, G4H, E_, bias4h);

    for (int t = 0; t < TM1; ++t){
        attn_k<<<dim3(B_,2), 512, 0, stream>>>(wa_b, a_b, hWbuf, v, beta_W, beta_b,
                                               xcat_b, alphas, ebuf, ebar, t);
        gates_k<<<dim3(32,4), 256, 0, stream>>>(xcat_b, WcatT, gp);
        lstm_hw_k<<<B_, 512, 0, stream>>>(gp, embWih, cbuf, xcat_b, Hall, WhcT, hWbuf, t);
    }
    // logits = Hall @ fc_W + fc_b   (2432 x 10000 x 512), NT stores + XCD swizzle
    gemm_mfma<0,1,1,1><<<dim3(1520), 256, 0, stream>>>(Hall, H_, fcWT, H_, out, V_, V_, H_, fc_b);
}

// Round 7
// 1054.187 us; speedup vs baseline: 2.1158x; 1.0822x over previous
//
#include <hip/hip_runtime.h>
#include <hip/hip_bf16.h>
#include <math.h>

#define B_ 128
#define L_ 196
#define D_ 512
#define T_ 20
#define V_ 10000
#define E_ 256
#define H_ 512
#define A_ 512
#define TM1 19
#define ROWS (TM1*B_)      /* 2432 */
#define G4H 2048
#define KCAT 1024
#define LH 98

typedef unsigned short ushort_t;
typedef __attribute__((ext_vector_type(8))) short bf16x8;
typedef __attribute__((ext_vector_type(4))) float f32x4;

__device__ __forceinline__ float fast_tanh(float x){
    float ax = fabsf(x);
    float e = __expf(-2.f*ax);
    float r = __builtin_amdgcn_rcpf(1.f + e);
    return copysignf((1.f - e)*r, x);
}
__device__ __forceinline__ float sigmoidf_(float x){
    return __builtin_amdgcn_rcpf(1.f + __expf(-x));
}
__device__ __forceinline__ ushort_t f2b(float f){
    union{float f; unsigned u;} x; x.f = f;
    unsigned r = x.u + 0x7fffu + ((x.u>>16)&1u);
    return (ushort_t)(r>>16);
}
__device__ __forceinline__ float b2f(ushort_t h){
    union{unsigned u; float f;} x; x.u = ((unsigned)h)<<16;
    return x.f;
}
__device__ __forceinline__ float b2f_lo(unsigned u){ union{unsigned u; float f;} x; x.u = u<<16; return x.f; }
__device__ __forceinline__ float b2f_hi(unsigned u){ union{unsigned u; float f;} x; x.u = u & 0xffff0000u; return x.f; }

// ================= bf16 MFMA GEMM: C = A @ BT^T (+bias), swizzled LDS =================
template<int OUT_BF16, int HAS_BIAS, int NT, int SWZ>
__global__ __launch_bounds__(256)
void gemm_mfma(const ushort_t* __restrict__ A, int lda,
               const ushort_t* __restrict__ BT, int ldb,
               void* __restrict__ Cout, int ldc,
               int N, int K, const float* __restrict__ bias)
{
    __shared__ ushort_t As[128*32];
    __shared__ ushort_t Bs[128*32];
    int bm, bn;
    if (SWZ){
        int bid = blockIdx.x;                 // 0..1519
        int swz = (bid & 7)*190 + (bid >> 3); // XCD-contiguous chunks
        int mt = swz % 19, nt = swz / 19;     // nt 0..79
        if (nt >= 79) return;
        bm = mt*128; bn = nt*128;
    } else {
        bm = blockIdx.y * 128; bn = blockIdx.x * 128;
    }
    const int tid = threadIdx.x;
    const int lane = tid & 63;
    const int wave = tid >> 6;
    const int wm = (wave >> 1) * 64;
    const int wn = (wave & 1) * 64;
    const int lrow = lane & 15;
    const int lk8  = (lane >> 4) * 8;
    const int srow = tid >> 2;
    const int skq  = ((tid & 3) * 8) ^ ((srow & 3) << 3);   // write-side swizzle
    const int skq0 = (tid & 3) * 8;

    f32x4 acc[4][4];
    #pragma unroll
    for (int i=0;i<4;i++)
        #pragma unroll
        for (int j=0;j<4;j++) acc[i][j] = (f32x4){0.f,0.f,0.f,0.f};

    const ushort_t* Abase = A  + (size_t)(bm+srow)*lda + skq0;
    const ushort_t* Bbase = BT + (size_t)(bn+srow)*ldb + skq0;

    for (int k0 = 0; k0 < K; k0 += 32) {
        int4 a0 = *(const int4*)(Abase + k0);
        int4 a1 = *(const int4*)(Abase + (size_t)64*lda + k0);
        int4 b0 = *(const int4*)(Bbase + k0);
        int4 b1 = *(const int4*)(Bbase + (size_t)64*ldb + k0);
        __syncthreads();
        *(int4*)&As[srow*32 + skq]      = a0;
        *(int4*)&As[(srow+64)*32 + skq] = a1;
        *(int4*)&Bs[srow*32 + skq]      = b0;
        *(int4*)&Bs[(srow+64)*32 + skq] = b1;
        __syncthreads();
        bf16x8 af[4], bfr[4];
        #pragma unroll
        for (int i=0;i<4;i++){
            int r = wm + i*16 + lrow;
            af[i]  = *(bf16x8*)&As[r*32 + (lk8 ^ ((r & 3) << 3))];
        }
        #pragma unroll
        for (int j=0;j<4;j++){
            int r = wn + j*16 + lrow;
            bfr[j] = *(bf16x8*)&Bs[r*32 + (lk8 ^ ((r & 3) << 3))];
        }
        #pragma unroll
        for (int i=0;i<4;i++)
            #pragma unroll
            for (int j=0;j<4;j++)
                acc[i][j] = __builtin_amdgcn_mfma_f32_16x16x32_bf16(af[i], bfr[j], acc[i][j], 0, 0, 0);
    }

    const int rq = (lane >> 4) * 4;
    #pragma unroll
    for (int j=0;j<4;j++){
        int col = bn + wn + j*16 + lrow;
        if (col >= N) continue;
        float bv = HAS_BIAS ? bias[col] : 0.f;
        #pragma unroll
        for (int i=0;i<4;i++){
            #pragma unroll
            for (int q=0;q<4;q++){
                int row = bm + wm + i*16 + rq + q;
                float v = acc[i][j][q] + bv;
                if (OUT_BF16) ((ushort_t*)Cout)[(size_t)row*ldc + col] = f2b(v);
                else if (NT)  __builtin_nontemporal_store(v, &((float*)Cout)[(size_t)row*ldc + col]);
                else          ((float*)Cout)[(size_t)row*ldc + col] = v;
            }
        }
    }
}

// ============ f32 tile GEMM (init path): C = tanh(A@B + bias), z picks job ============
__global__ __launch_bounds__(256) void gemm64t2(const float* __restrict__ A, int lda,
                       const float* __restrict__ B0, const float* __restrict__ B1, int ldb,
                       float* __restrict__ C0, float* __restrict__ C1, int ldc,
                       const float* __restrict__ bias0, const float* __restrict__ bias1)
{
    const float* Bm  = blockIdx.z ? B1 : B0;
    float* C         = blockIdx.z ? C1 : C0;
    const float* bias= blockIdx.z ? bias1 : bias0;
    __shared__ float As[16][65];
    __shared__ float Bs[16][65];
    int bm = blockIdx.y*64, bn = blockIdx.x*64;
    int tid = threadIdx.x;
    int tx = tid & 15, ty = tid >> 4;
    float acc[4][4] = {};
    for (int k0 = 0; k0 < D_; k0 += 16) {
        {
            int r  = tid >> 2;
            int kq = (tid & 3) * 4;
            float4 va = *(const float4*)(A + (size_t)(bm+r)*lda + k0 + kq);
            As[kq+0][r]=va.x; As[kq+1][r]=va.y; As[kq+2][r]=va.z; As[kq+3][r]=va.w;
        }
        {
            int kk = tid >> 4;
            int nq = (tid & 15) * 4;
            float4 vb = *(const float4*)(Bm + (size_t)(k0+kk)*ldb + bn + nq);
            Bs[kk][nq+0]=vb.x; Bs[kk][nq+1]=vb.y; Bs[kk][nq+2]=vb.z; Bs[kk][nq+3]=vb.w;
        }
        __syncthreads();
        #pragma unroll
        for (int k = 0; k < 16; ++k) {
            float a0[4], b0[4];
            #pragma unroll
            for (int i=0;i<4;i++) a0[i] = As[k][ty*4+i];
            #pragma unroll
            for (int j=0;j<4;j++) b0[j] = Bs[k][tx*4+j];
            #pragma unroll
            for (int i=0;i<4;i++)
                #pragma unroll
                for (int j=0;j<4;j++)
                    acc[i][j] = fmaf(a0[i], b0[j], acc[i][j]);
        }
        __syncthreads();
    }
    #pragma unroll
    for (int i=0;i<4;i++){
        int row = bm + ty*4 + i;
        #pragma unroll
        for (int j=0;j<4;j++){
            int col = bn + tx*4 + j;
            C[(size_t)row*ldc + col] = fast_tanh(acc[i][j] + bias[col]);
        }
    }
}

// ================= combined transpose+cvt (all weights in one launch) =================
struct TJob { const float* src; const float* src2; ushort_t* dst;
              int lds, Ksz, Nsz, koff, ldk, nx, nblk; };
struct TJobs { TJob j[6]; };

__global__ __launch_bounds__(256) void combo_trans_k(TJobs J){
    __shared__ float t[32][33];
    int bid = blockIdx.x;
    int ji = 0;
    while (bid >= J.j[ji].nblk){ bid -= J.j[ji].nblk; ji++; }
    const TJob jb = J.j[ji];
    int n0 = (bid % jb.nx)*32, k0 = (bid / jb.nx)*32;
    int tx = threadIdx.x & 31, ty = threadIdx.x >> 5;
    #pragma unroll
    for (int kk = ty; kk < 32; kk += 8){
        int k = k0 + kk, n = n0 + tx;
        float v = 0.f;
        if (k < jb.Ksz && n < jb.Nsz){
            v = jb.src[(size_t)k*jb.lds + n];
            if (jb.src2) v += jb.src2[(size_t)k*jb.lds + n];
        }
        t[kk][tx] = v;
    }
    __syncthreads();
    #pragma unroll
    for (int nn = ty; nn < 32; nn += 8){
        int n = n0 + nn, k = k0 + tx;
        if (k < jb.Ksz) jb.dst[(size_t)n*jb.ldk + jb.koff + k] = f2b(t[tx][nn]);
    }
}

// one pass over a: column means + bf16 copy; block 256 also does bias4h + ebar init
__global__ __launch_bounds__(256) void mean_cvt_k(const float* __restrict__ a, ushort_t* __restrict__ a_b,
                                                  float* __restrict__ mc,
                                                  const float* __restrict__ b_ih, const float* __restrict__ b_hh,
                                                  float* __restrict__ bias4h, unsigned* __restrict__ ebar){
    if (blockIdx.x == 256){
        for (int k = threadIdx.x; k < G4H; k += 256) bias4h[k] = b_ih[k] + b_hh[k];
        if (threadIdx.x < B_) ebar[threadIdx.x] = 0u;
        return;
    }
    int idx = blockIdx.x*256 + threadIdx.x;   // b*512 + d
    int b = idx >> 9, d = idx & 511;
    const float* p = a + (size_t)b*L_*D_ + d;
    ushort_t* q = a_b + (size_t)b*L_*D_ + d;
    float s = 0.f;
    for (int l=0;l<L_;l++){ float v = p[(size_t)l*D_]; s += v; q[(size_t)l*D_] = f2b(v); }
    mc[idx] = s * (1.f/(float)L_);
}

__global__ void gather_emb(const int* __restrict__ captions, const float* __restrict__ embW,
                           ushort_t* __restrict__ xemb){
    int i = blockIdx.x;                 // t*B + b
    int t = i / B_, b = i - t*B_;
    int cap = captions[b*T_ + t];
    float4 v = ((const float4*)(embW + (size_t)cap*E_))[threadIdx.x];
    ushort_t r[4] = {f2b(v.x),f2b(v.y),f2b(v.z),f2b(v.w)};
    *(uint2*)(xemb + (size_t)i*E_ + threadIdx.x*4) = *(uint2*)r;
}

// h0: cvt to xcat + full hWp0 + zero hWp1;  grid B x 512
__global__ __launch_bounds__(512) void hw0cvt_k(const float* __restrict__ h0f,
                        const ushort_t* __restrict__ WhcT,
                        ushort_t* __restrict__ xcat, float* __restrict__ hWp){
    int b = blockIdx.x, tid = threadIdx.x;
    int lane = tid & 63, wave = tid >> 6;
    __shared__ ushort_t hls[512];
    float hv = h0f[b*H_ + tid];
    ushort_t hb = f2b(hv);
    xcat[(size_t)b*KCAT + D_ + tid] = hb;
    hls[tid] = hb;
    hWp[(size_t)(b*2+1)*512 + tid] = 0.f;
    __syncthreads();
    int wn = wave * 64;
    int col16 = lane & 15;
    int khi = (lane >> 4) * 8;
    bool a_on = (col16 == 0);
    f32x4 acc[4];
    #pragma unroll
    for (int f=0;f<4;f++) acc[f] = (f32x4){0.f,0.f,0.f,0.f};
    for (int kk=0; kk<16; kk++){
        bf16x8 af = (bf16x8){0,0,0,0,0,0,0,0};
        if (a_on) af = *(const bf16x8*)&hls[kk*32 + khi];
        #pragma unroll
        for (int f=0;f<4;f++){
            bf16x8 bf = *(const bf16x8*)(WhcT + (size_t)(wn + f*16 + col16)*512 + kk*32 + khi);
            acc[f] = __builtin_amdgcn_mfma_f32_16x16x32_bf16(af, bf, acc[f], 0, 0, 0);
        }
    }
    if (lane < 16){
        #pragma unroll
        for (int f=0;f<4;f++) hWp[(size_t)(b*2+0)*512 + wn + f*16 + lane] = acc[f][0];
    }
}

// ================= mega: lstm(t-1) + hW-partial + attention(t) =================
// grid (B_, 2) x 512; 2 pair-syncs per step via monotonic ebar[b]
__global__ __launch_bounds__(512) void mega2_k(const ushort_t* __restrict__ wa,
                        const ushort_t* __restrict__ a_b,
                        const float* __restrict__ v,
                        const float* __restrict__ beta_W, const float* __restrict__ beta_b,
                        const ushort_t* __restrict__ WhcT,
                        const float* __restrict__ gp, const float* __restrict__ embWih,
                        float* __restrict__ cbuf, float* __restrict__ hWp,
                        ushort_t* __restrict__ xcat, ushort_t* __restrict__ Hall,
                        float* __restrict__ alphas_out, float* __restrict__ ebuf,
                        unsigned* __restrict__ ebar, int t)
{
    const int b = blockIdx.x, half = blockIdx.y;
    const int tid = threadIdx.x;
    const int lane = tid & 63, wave = tid >> 6;
    __shared__ ushort_t hls[256];
    __shared__ float red[512];
    __shared__ float al_s[224];
    __shared__ float part[2][256];

    // ---- phase L: lstm for own j-half + hW K-partial (skip at t==0) ----
    if (t > 0){
        if (tid < 256){
            const int j = half*256 + tid;
            const float* eb = embWih + ((size_t)((t-1)*B_ + b))*G4H;
            float gi = eb[j], gf = eb[H_+j], gg = eb[2*H_+j], go = eb[3*H_+j];
            #pragma unroll
            for (int ks=0; ks<8; ks++){
                const float* g = gp + ((size_t)(ks*B_ + b))*G4H;
                gi += g[j]; gf += g[H_+j]; gg += g[2*H_+j]; go += g[3*H_+j];
            }
            float ig = sigmoidf_(gi), fg = sigmoidf_(gf);
            float g2 = fast_tanh(gg), og = sigmoidf_(go);
            float c = fg*cbuf[b*H_+j] + ig*g2;
            float h = og*fast_tanh(c);
            cbuf[b*H_+j] = c;
            ushort_t hb = f2b(h);
            xcat[(size_t)b*KCAT + D_ + j] = hb;
            Hall[((size_t)(t-1)*B_ + b)*H_ + j] = hb;
            hls[tid] = hb;
        }
        __syncthreads();
        // hWp[half] = h_half @ Whc[half*256 : half*256+256, :]   (K=256 slice)
        int wn = wave * 64;
        int col16 = lane & 15;
        int khi = (lane >> 4) * 8;
        bool a_on = (col16 == 0);
        f32x4 acc[4];
        #pragma unroll
        for (int f=0;f<4;f++) acc[f] = (f32x4){0.f,0.f,0.f,0.f};
        #pragma unroll
        for (int kk=0; kk<8; kk++){
            bf16x8 af = (bf16x8){0,0,0,0,0,0,0,0};
            if (a_on) af = *(const bf16x8*)&hls[kk*32 + khi];
            #pragma unroll
            for (int f=0;f<4;f++){
                bf16x8 bf = *(const bf16x8*)(WhcT + (size_t)(wn + f*16 + col16)*512 + half*256 + kk*32 + khi);
                acc[f] = __builtin_amdgcn_mfma_f32_16x16x32_bf16(af, bf, acc[f], 0, 0, 0);
            }
        }
        if (lane < 16){
            #pragma unroll
            for (int f=0;f<4;f++) hWp[(size_t)(b*2+half)*512 + wn + f*16 + lane] = acc[f][0];
        }
    }
    // ---- pair sync 1: h + hWp complete for both halves ----
    __syncthreads();
    if (tid == 0){
        __threadfence();
        atomicAdd(&ebar[b], 1u);
        const unsigned tgt = 2u*(unsigned)(2*t+1);
        while (__hip_atomic_load(&ebar[b], __ATOMIC_ACQUIRE, __HIP_MEMORY_SCOPE_AGENT) < tgt)
            __builtin_amdgcn_s_sleep(1);
    }
    __syncthreads();
    // ---- phase E: e over own l-half ----
    {
        const float* hp0 = hWp + (size_t)(b*2+0)*512 + lane*8;
        const float* hp1 = hWp + (size_t)(b*2+1)*512 + lane*8;
        float4 p00 = *(const float4*)hp0, p01 = *(const float4*)(hp0+4);
        float4 p10 = *(const float4*)hp1, p11 = *(const float4*)(hp1+4);
        float4 hw0 = make_float4(p00.x+p10.x, p00.y+p10.y, p00.z+p10.z, p00.w+p10.w);
        float4 hw1 = make_float4(p01.x+p11.x, p01.y+p11.y, p01.z+p11.z, p01.w+p11.w);
        const float* vp = v + lane*8;
        float4 v0 = *(const float4*)vp, v1 = *(const float4*)(vp+4);
        const int l0 = half*LH;
        for (int r = wave; r < LH; r += 8){
            int4 raw = *(const int4*)(wa + (((size_t)(b*L_ + l0 + r))<<9) + lane*8);
            const unsigned* u = (const unsigned*)&raw;
            float s;
            s  = fast_tanh(b2f_lo(u[0]) + hw0.x)*v0.x;
            s += fast_tanh(b2f_hi(u[0]) + hw0.y)*v0.y;
            s += fast_tanh(b2f_lo(u[1]) + hw0.z)*v0.z;
            s += fast_tanh(b2f_hi(u[1]) + hw0.w)*v0.w;
            s += fast_tanh(b2f_lo(u[2]) + hw1.x)*v1.x;
            s += fast_tanh(b2f_hi(u[2]) + hw1.y)*v1.y;
            s += fast_tanh(b2f_lo(u[3]) + hw1.z)*v1.z;
            s += fast_tanh(b2f_hi(u[3]) + hw1.w)*v1.w;
            #pragma unroll
            for (int off=32; off; off>>=1) s += __shfl_down(s, off);
            if (lane==0) ebuf[b*L_ + l0 + r] = s;
        }
    }
    // ---- pair sync 2: e complete ----
    __syncthreads();
    if (tid == 0){
        __threadfence();
        atomicAdd(&ebar[b], 1u);
        const unsigned tgt = 2u*(unsigned)(2*t+2);
        while (__hip_atomic_load(&ebar[b], __ATOMIC_ACQUIRE, __HIP_MEMORY_SCOPE_AGENT) < tgt)
            __builtin_amdgcn_s_sleep(1);
    }
    __syncthreads();
    // ---- softmax over 196 (redundant per half) ----
    float ev = (tid < L_) ? ebuf[b*L_ + tid] : -3.0e38f;
    red[tid] = ev; __syncthreads();
    #pragma unroll
    for (int s=256; s; s>>=1){ if (tid<s) red[tid] = fmaxf(red[tid], red[tid+s]); __syncthreads(); }
    float m = red[0]; __syncthreads();
    float pr = (tid < L_) ? __expf(ev - m) : 0.f;
    red[tid] = pr; __syncthreads();
    #pragma unroll
    for (int s=256; s; s>>=1){ if (tid<s) red[tid] += red[tid+s]; __syncthreads(); }
    float inv = 1.f / red[0];
    __syncthreads();
    if (tid < L_) al_s[tid] = pr*inv;
    const int l0 = half*LH;
    if (tid >= l0 && tid < l0 + LH)
        __builtin_nontemporal_store(pr*inv, alphas_out + (size_t)b*TM1*L_ + (size_t)t*L_ + tid);
    // ---- beta ----
    float dv = b2f(xcat[(size_t)b*KCAT + D_ + tid]) * beta_W[tid];
    red[tid] = dv; __syncthreads();
    #pragma unroll
    for (int s=256; s; s>>=1){ if (tid<s) red[tid] += red[tid+s]; __syncthreads(); }
    float beta = sigmoidf_(red[0] + beta_b[0]);
    __syncthreads();
    // ---- ctx: 256 d's per block, l split by tid>>8 ----
    const int d  = half*256 + (tid & 255);
    const int lr = tid >> 8;
    const ushort_t* pa = a_b + (((size_t)(b*L_ + lr*LH))<<9) + d;
    float s0 = 0.f;
    #pragma unroll 7
    for (int i=0; i<LH; ++i) s0 = fmaf(al_s[lr*LH + i], b2f(pa[(size_t)i*512]), s0);
    part[lr][tid & 255] = s0;
    __syncthreads();
    if (tid < 256)
        xcat[(size_t)b*KCAT + half*256 + tid] = f2b(beta*(part[0][tid] + part[1][tid]));
}

// gates partials: grid (32, 8) x 256; tile M128 x N64, K-chunk 128
__global__ __launch_bounds__(256) void gates_k(const ushort_t* __restrict__ xcat,
                        const ushort_t* __restrict__ WcatT, float* __restrict__ gp){
    __shared__ ushort_t As[128*32];
    __shared__ ushort_t Bs[64*32];
    const int bn = blockIdx.x*64;
    const int ks = blockIdx.y;
    const int tid = threadIdx.x;
    const int lane = tid & 63, wave = tid >> 6;
    const int wm = wave*32;
    const int lrow = lane & 15;
    const int lk8 = (lane >> 4) * 8;
    f32x4 acc[2][4];
    #pragma unroll
    for (int i=0;i<2;i++)
        #pragma unroll
        for (int j=0;j<4;j++) acc[i][j] = (f32x4){0.f,0.f,0.f,0.f};

    for (int kk = 0; kk < 4; ++kk){
        int k0 = ks*128 + kk*32;
        int c0 = 2*tid;
        int r0 = c0 >> 2,  kq0 = (c0 & 3)*8;
        int r1 = (c0+1) >> 2, kq1 = ((c0+1) & 3)*8;
        int4 a0 = *(const int4*)(xcat + (size_t)r0*KCAT + k0 + kq0);
        int4 a1 = *(const int4*)(xcat + (size_t)r1*KCAT + k0 + kq1);
        int rb = tid >> 2, kqb = (tid & 3)*8;
        int4 b0 = *(const int4*)(WcatT + (size_t)(bn+rb)*KCAT + k0 + kqb);
        __syncthreads();
        *(int4*)&As[r0*32 + kq0] = a0;
        *(int4*)&As[r1*32 + kq1] = a1;
        *(int4*)&Bs[rb*32 + kqb] = b0;
        __syncthreads();
        bf16x8 af[2], bfr[4];
        #pragma unroll
        for (int i=0;i<2;i++) af[i] = *(bf16x8*)&As[(wm + i*16 + lrow)*32 + lk8];
        #pragma unroll
        for (int j=0;j<4;j++) bfr[j] = *(bf16x8*)&Bs[(j*16 + lrow)*32 + lk8];
        #pragma unroll
        for (int i=0;i<2;i++)
            #pragma unroll
            for (int j=0;j<4;j++)
                acc[i][j] = __builtin_amdgcn_mfma_f32_16x16x32_bf16(af[i], bfr[j], acc[i][j], 0, 0, 0);
    }
    const int rq = (lane >> 4) * 4;
    #pragma unroll
    for (int i=0;i<2;i++){
        #pragma unroll
        for (int j=0;j<4;j++){
            int gcol = bn + j*16 + lrow;
            #pragma unroll
            for (int q=0;q<4;q++){
                int grow = wm + i*16 + rq + q;
                gp[((size_t)(ks*B_ + grow))*G4H + gcol] = acc[i][j][q];
            }
        }
    }
}

// final lstm (h_19 -> Hall[18]); grid B x 512
__global__ __launch_bounds__(512) void lstmfin_k(const float* __restrict__ gp, const float* __restrict__ embWih,
                       const float* __restrict__ cbuf, ushort_t* __restrict__ Hall){
    int b = blockIdx.x, j = threadIdx.x;
    const float* eb = embWih + ((size_t)(18*B_ + b))*G4H;
    float gi = eb[j], gf = eb[H_+j], gg = eb[2*H_+j], go = eb[3*H_+j];
    #pragma unroll
    for (int ks=0; ks<8; ks++){
        const float* g = gp + ((size_t)(ks*B_ + b))*G4H;
        gi += g[j]; gf += g[H_+j]; gg += g[2*H_+j]; go += g[3*H_+j];
    }
    float ig = sigmoidf_(gi), fg = sigmoidf_(gf);
    float g2 = fast_tanh(gg), og = sigmoidf_(go);
    float c = fg*cbuf[b*H_+j] + ig*g2;
    float h = og*fast_tanh(c);
    Hall[((size_t)18*B_ + b)*H_ + j] = f2b(h);
}

extern "C" void kernel_launch(void* const* d_in, const int* in_sizes, int n_in,
                              void* d_out, int out_size, void* d_ws, size_t ws_size,
                              hipStream_t stream) {
    const float* a      = (const float*)d_in[0];
    const int*   caps   = (const int*)  d_in[1];
    const float* embW   = (const float*)d_in[3];
    const float* Wa     = (const float*)d_in[4];
    const float* Wh     = (const float*)d_in[5];
    const float* Wc     = (const float*)d_in[6];
    const float* v      = (const float*)d_in[7];
    const float* beta_W = (const float*)d_in[8];
    const float* beta_b = (const float*)d_in[9];
    const float* W_ih   = (const float*)d_in[10];
    const float* W_hh   = (const float*)d_in[11];
    const float* b_ih   = (const float*)d_in[12];
    const float* b_hh   = (const float*)d_in[13];
    const float* fc_W   = (const float*)d_in[14];
    const float* fc_b   = (const float*)d_in[15];
    const float* iWh    = (const float*)d_in[16];
    const float* ibh    = (const float*)d_in[17];
    const float* iWc    = (const float*)d_in[18];
    const float* ibc    = (const float*)d_in[19];

    float* out    = (float*)d_out;
    float* alphas = out + (size_t)ROWS*V_;

    // d_out scratch (dead before final logits GEMM overwrites it)
    char* ob = (char*)d_out;
    ushort_t* wa_b   = (ushort_t*)(ob);               // 25,690,112 B
    ushort_t* a_b    = (ushort_t*)(ob + 25690112);    // 25,690,112 B
    float*    embWih = (float*)   (ob + 51380224);    // 19,922,944 B (ends 71.3MB < 97.28MB)

    // d_ws layout (byte offsets)
    char* wb = (char*)d_ws;
    float* mean_ctx = (float*)(wb);                 // 262144
    float* cbuf     = (float*)(wb + 262144);        // 262144
    float* h0f      = (float*)(wb + 524288);        // 262144
    float* hWp      = (float*)(wb + 786432);        // 524288 (128*2*512 f32)
    float* ebuf     = (float*)(wb + 1310720);       // 102400
    float* bias4h   = (float*)(wb + 1413120);       // 8192
    unsigned* ebar  = (unsigned*)(wb + 1421312);    // 1024
    float* gp       = (float*)(wb + 1422336);       // 8388608 (8 ksplits)
    ushort_t* xcat_b = (ushort_t*)(wb + 9810944);   // 262144
    ushort_t* xemb_b = (ushort_t*)(wb + 10073088);  // 1245184
    ushort_t* Hall   = (ushort_t*)(wb + 11318272);  // 2490368
    ushort_t* WaT    = (ushort_t*)(wb + 13808640);  // 524288
    ushort_t* WhcT   = (ushort_t*)(wb + 14332928);  // 524288
    ushort_t* WihT   = (ushort_t*)(wb + 14857216);  // 1048576
    ushort_t* WcatT  = (ushort_t*)(wb + 15905792);  // 4194304
    ushort_t* fcWT   = (ushort_t*)(wb + 20100096);  // 10354688 -> ends ~29.0MB

    // ---- prep (7 launches) ----
    TJobs J;
    J.j[0] = { Wa,   nullptr, WaT,  512, 512, 512,  0,   512,  16, 256 };
    J.j[1] = { Wh,   Wc,      WhcT, 512, 512, 512,  0,   512,  16, 256 };
    J.j[2] = { W_ih, nullptr, WihT, G4H, 256, G4H,  0,   256,  64, 512 };
    J.j[3] = { W_ih + (size_t)E_*G4H, nullptr, WcatT, G4H, 512, G4H, 0,   KCAT, 64, 1024 };
    J.j[4] = { W_hh, nullptr, WcatT, G4H, 512, G4H,  512, KCAT, 64, 1024 };
    J.j[5] = { fc_W, nullptr, fcWT, V_,  512, V_,   0,   512,  316, 5056 };
    combo_trans_k<<<8128, 256, 0, stream>>>(J);
    mean_cvt_k<<<257, 256, 0, stream>>>(a, a_b, mean_ctx, b_ih, b_hh, bias4h, ebar);
    gather_emb<<<ROWS, 64, 0, stream>>>(caps, embW, xemb_b);
    gemm64t2<<<dim3(8,2,2), 256, 0, stream>>>(mean_ctx, D_, iWh, iWc, H_, h0f, cbuf, H_, ibh, ibc);
    hw0cvt_k<<<B_, 512, 0, stream>>>(h0f, WhcT, xcat_b, hWp);
    // wa_b = bf16(a @ Wa)    (25088 x 512 x 512)
    gemm_mfma<1,0,0,0><<<dim3(4,196), 256, 0, stream>>>(a_b, D_, WaT, D_, wa_b, A_, A_, D_, nullptr);
    // embWih = xemb @ W_ih[:E] + (b_ih+b_hh)   (2432 x 2048 x 256)
    gemm_mfma<0,1,0,0><<<dim3(16,19), 256, 0, stream>>>(xemb_b, E_, WihT, E_, embWih, G4H, G4H, E_, bias4h);

    // ---- loop: 2 kernels/step ----
    for (int t = 0; t < TM1; ++t){
        mega2_k<<<dim3(B_,2), 512, 0, stream>>>(wa_b, a_b, v, beta_W, beta_b, WhcT,
                                                gp, embWih, cbuf, hWp, xcat_b, Hall,
                                                alphas, ebuf, ebar, t);
        gates_k<<<dim3(32,8), 256, 0, stream>>>(xcat_b, WcatT, gp);
    }
    lstmfin_k<<<B_, 512, 0, stream>>>(gp, embWih, cbuf, Hall);

    // logits = Hall @ fc_W + fc_b   (2432 x 10000 x 512), NT stores + XCD swizzle
    gemm_mfma<0,1,1,1><<<dim3(1520), 256, 0, stream>>>(Hall, H_, fcWT, H_, out, V_, V_, H_, fc_b);
}